// Round 5
// baseline (87.202 us; speedup 1.0000x reference)
//
#include <hip/hip_runtime.h>
#include <math.h>

#define IMG_H 512
#define IMG_W 512
#define TH 8                 // output rows per block
#define KR 5                 // radius
#define KS 11                // taps
#define LW2 524              // f32x2 cols: global cols -6..517 at idx col+6
#define NTHREADS 512

typedef float f32x2 __attribute__((ext_vector_type(2)));

struct W22 { float w[2 * KS]; };   // w[2k] == w[2k+1] == gaussian tap k

// Fused SSIM band kernel: one 512x8 full-width output band per block.
// LDS holds TWO interleaved float2 fields:
//   sm[r][c] = (conv_v(a), conv_v(b))        -> horizontal conv gives (mu1, mu2)
//   sv[r][c] = (conv_v(a^2+b^2), conv_v(ab)) -> gives (E[a^2+b^2], E[ab])
// Pairs share taps exactly -> every FMA is a v_pk_fma_f32 with no packing movs.
__global__ __launch_bounds__(NTHREADS)
void ssim_tile_kernel(const float* __restrict__ img1, const float* __restrict__ img2,
                      float* __restrict__ bsums, W22 wt) {
    __shared__ __align__(16) f32x2 sm[TH][LW2];   // 33,536 B
    __shared__ __align__(16) f32x2 sv[TH][LW2];   // 33,536 B
    __shared__ float redw[NTHREADS / 64];

    const int row0  = blockIdx.y * TH;
    const int plane = blockIdx.z;
    const float* __restrict__ p1 = img1 + (size_t)plane * (IMG_H * IMG_W);
    const float* __restrict__ p2 = img2 + (size_t)plane * (IMG_H * IMG_W);
    const int tid = threadIdx.x;
    const int r0  = row0 - KR;

    // Zero-fill the 12 alignment-halo cols (idx 0..5 = cols -6..-1, 518..523 = 512..517).
    if (tid < 128) {
        const int h = tid & 15, r = tid >> 4;
        if (h < 12) {
            const int ci = (h < 6) ? h : (h + 512);
            sm[r][ci] = (f32x2){0.f, 0.f};
            sv[r][ci] = (f32x2){0.f, 0.f};
        }
    }

    // ---- Phase A: vertical 11-tap conv, one column per thread, packed accs ----
    f32x2 accm[TH], accs[TH];
    #pragma unroll
    for (int r = 0; r < TH; ++r) { accm[r] = (f32x2){0.f, 0.f}; accs[r] = (f32x2){0.f, 0.f}; }

    const float* __restrict__ g1 = p1 + tid;
    const float* __restrict__ g2 = p2 + tid;
    #pragma unroll
    for (int j = 0; j < TH + 2 * KR; ++j) {        // 18 input rows
        const int rr = r0 + j;                     // block-uniform -> scalar branch
        if (rr >= 0 && rr < IMG_H) {
            const float a = g1[rr * IMG_W];
            const float b = g2[rr * IMG_W];
            f32x2 mv; mv.x = a;               mv.y = b;
            f32x2 pv; pv.x = fmaf(a, a, b*b); pv.y = a * b;
            #pragma unroll
            for (int r = 0; r < TH; ++r) {
                const int k = j - r;               // compile-time after unroll
                if (k >= 0 && k < KS) {
                    f32x2 wv; wv.x = wt.w[2*k]; wv.y = wt.w[2*k + 1];
                    accm[r] = __builtin_elementwise_fma(wv, mv, accm[r]);
                    accs[r] = __builtin_elementwise_fma(wv, pv, accs[r]);
                }
            }
        }
    }
    #pragma unroll
    for (int r = 0; r < TH; ++r) {
        sm[r][tid + 6] = accm[r];
        sv[r][tid + 6] = accs[r];
    }
    __syncthreads();

    // ---- Phase B: horizontal conv + SSIM map; 2 chunks of (1 row x 4 cols) ----
    const float C1f = 0.0001f;   // 0.01^2
    const float C2f = 0.0009f;   // 0.03^2
    const int r = tid >> 6;      // 8 rows x 64 lanes

    float lsum = 0.f;
    #pragma unroll
    for (int ch = 0; ch < 2; ++ch) {
        const int c4 = ((tid & 63) << 2) + ch * 256;   // output col base

        // load 16 f32x2 (cols c4-6 .. c4+9) per array as 8 float4
        f32x2 xm[16], xs[16];
        {
            const float4* rpm = (const float4*)&sm[r][c4];   // idx c4 <-> col c4-6
            const float4* rps = (const float4*)&sv[r][c4];
            #pragma unroll
            for (int i = 0; i < 8; ++i) {
                const float4 qm = rpm[i], qs = rps[i];
                xm[2*i].x = qm.x; xm[2*i].y = qm.y; xm[2*i+1].x = qm.z; xm[2*i+1].y = qm.w;
                xs[2*i].x = qs.x; xs[2*i].y = qs.y; xs[2*i+1].x = qs.z; xs[2*i+1].y = qs.w;
            }
        }

        // output col c4+j needs cols c4+j-5..c4+j+5 -> x[j+1 .. j+11]
        #pragma unroll
        for (int j = 0; j < 4; ++j) {
            f32x2 w0; w0.x = wt.w[0]; w0.y = wt.w[1];
            f32x2 cmu = w0 * xm[j + 1];
            f32x2 csv = w0 * xs[j + 1];
            #pragma unroll
            for (int k = 1; k < KS; ++k) {
                f32x2 wv; wv.x = wt.w[2*k]; wv.y = wt.w[2*k + 1];
                cmu = __builtin_elementwise_fma(wv, xm[j + 1 + k], cmu);
                csv = __builtin_elementwise_fma(wv, xs[j + 1 + k], csv);
            }
            const float m1 = cmu.x, m2 = cmu.y;
            const float mu11 = m1 * m1;
            const float mu22 = m2 * m2;
            const float mu12 = m1 * m2;
            const float t     = mu11 + mu22;
            const float sigpp = csv.x - t;           // sigma1_sq + sigma2_sq
            const float sig12 = csv.y - mu12;
            const float num = fmaf(2.f, mu12, C1f) * fmaf(2.f, sig12, C2f);
            const float den = (t + C1f) * (sigpp + C2f);
            lsum = fmaf(num, __builtin_amdgcn_rcpf(den), lsum);
        }
    }

    // ---- reduce: wave shuffle, then per-wave partials ----
    #pragma unroll
    for (int off = 32; off > 0; off >>= 1) lsum += __shfl_down(lsum, off);
    if ((tid & 63) == 0) redw[tid >> 6] = lsum;
    __syncthreads();
    if (tid == 0) {
        float t = 0.f;
        #pragma unroll
        for (int w = 0; w < NTHREADS / 64; ++w) t += redw[w];
        const int bid = blockIdx.z * gridDim.y + blockIdx.y;
        bsums[bid] = t;
    }
}

// Final reduce in double (fp32 sequential sum of the 1.26e7-magnitude total
// would exceed the 2.6e-4 threshold).
__global__ __launch_bounds__(256)
void ssim_reduce_kernel(const float4* __restrict__ bsums, int n4,
                        float* __restrict__ out, double inv_count) {
    __shared__ double red[256];
    double acc = 0.0;
    for (int i = threadIdx.x; i < n4; i += 256) {
        const float4 v = bsums[i];
        acc += (double)v.x + (double)v.y + (double)v.z + (double)v.w;
    }
    red[threadIdx.x] = acc;
    __syncthreads();
    #pragma unroll
    for (int off = 128; off > 0; off >>= 1) {
        if (threadIdx.x < off) red[threadIdx.x] += red[threadIdx.x + off];
        __syncthreads();
    }
    if (threadIdx.x == 0) out[0] = (float)(red[0] * inv_count);
}

extern "C" void kernel_launch(void* const* d_in, const int* in_sizes, int n_in,
                              void* d_out, int out_size, void* d_ws, size_t ws_size,
                              hipStream_t stream) {
    const float* img1 = (const float*)d_in[0];
    const float* img2 = (const float*)d_in[1];
    float* out = (float*)d_out;
    float* bsums = (float*)d_ws;

    // Gaussian weights, computed in double like the numpy reference, cast to f32.
    // Duplicated per tap so each tap is a ready-made 64-bit SGPR pair for pk_fma.
    W22 wt;
    {
        double g[KS], sum = 0.0;
        for (int i = 0; i < KS; ++i) {
            const double x = (double)(i - KR);
            g[i] = exp(-(x * x) / (2.0 * 1.5 * 1.5));
            sum += g[i];
        }
        for (int i = 0; i < KS; ++i) {
            wt.w[2*i]     = (float)(g[i] / sum);
            wt.w[2*i + 1] = (float)(g[i] / sum);
        }
    }

    const int NC = 16 * 3;
    const dim3 grid(1, IMG_H / TH, NC);    // 1 x 64 x 48 = 3072 blocks
    const int nblocks = grid.y * grid.z;

    ssim_tile_kernel<<<grid, NTHREADS, 0, stream>>>(img1, img2, bsums, wt);

    const double inv_count = 1.0 / ((double)NC * IMG_H * IMG_W);
    ssim_reduce_kernel<<<1, 256, 0, stream>>>((const float4*)bsums, nblocks / 4,
                                              out, inv_count);
}

// Round 6
// 82.979 us; speedup vs baseline: 1.0509x; 1.0509x over previous
//
#include <hip/hip_runtime.h>
#include <math.h>

#define IMG_H 512
#define IMG_W 512
#define TH 4                 // output rows per block
#define KR 5                 // radius
#define KS 11                // taps
#define LW2 524              // f32x2 cols: global cols -6..517 at idx col+6
#define NTHREADS 512

typedef float f32x2 __attribute__((ext_vector_type(2)));

struct W22 { float w[2 * KS]; };   // w[2k] == w[2k+1] == gaussian tap k

// Fused SSIM band kernel: one 512x4 full-width output band per block.
// LDS holds TWO interleaved f32x2 fields:
//   sm[r][c] = (conv_v(a), conv_v(b))        -> horizontal conv gives (mu1, mu2)
//   sv[r][c] = (conv_v(a^2+b^2), conv_v(ab)) -> gives (E[a^2+b^2], E[ab])
// Pairs share taps exactly -> every FMA is a v_pk_fma_f32 with no packing movs.
// LDS = 33.5 KB -> 4 blocks/CU (32 waves/CU) for latency hiding.
__global__ __launch_bounds__(NTHREADS)
void ssim_tile_kernel(const float* __restrict__ img1, const float* __restrict__ img2,
                      float* __restrict__ bsums, W22 wt) {
    __shared__ __align__(16) f32x2 sm[TH][LW2];   // 16,768 B
    __shared__ __align__(16) f32x2 sv[TH][LW2];   // 16,768 B
    __shared__ float redw[NTHREADS / 64];

    const int row0  = blockIdx.y * TH;
    const int plane = blockIdx.z;
    const float* __restrict__ p1 = img1 + (size_t)plane * (IMG_H * IMG_W);
    const float* __restrict__ p2 = img2 + (size_t)plane * (IMG_H * IMG_W);
    const int tid = threadIdx.x;
    const int r0  = row0 - KR;

    // Zero-fill the 12 alignment-halo cols (idx 0..5 = cols -6..-1, 518..523).
    if (tid < 12) {
        const int ci = (tid < 6) ? tid : (512 + tid);
        #pragma unroll
        for (int r = 0; r < TH; ++r) {
            sm[r][ci] = (f32x2){0.f, 0.f};
            sv[r][ci] = (f32x2){0.f, 0.f};
        }
    }

    // ---- Phase A: vertical 11-tap conv, one REAL column per thread (no tail,
    //      no column masking; halo cols handled by the zero-fill above) ----
    f32x2 accm[TH], accs[TH];
    #pragma unroll
    for (int r = 0; r < TH; ++r) { accm[r] = (f32x2){0.f, 0.f}; accs[r] = (f32x2){0.f, 0.f}; }

    const float* __restrict__ g1 = p1 + tid;
    const float* __restrict__ g2 = p2 + tid;
    #pragma unroll
    for (int j = 0; j < TH + 2 * KR; ++j) {        // 14 input rows
        const int rr = r0 + j;                     // block-uniform -> scalar branch
        if (rr >= 0 && rr < IMG_H) {
            const float a = g1[rr * IMG_W];
            const float b = g2[rr * IMG_W];
            f32x2 mv; mv.x = a;                mv.y = b;
            f32x2 pv; pv.x = fmaf(a, a, b*b);  pv.y = a * b;
            #pragma unroll
            for (int r = 0; r < TH; ++r) {
                const int k = j - r;               // compile-time after unroll
                if (k >= 0 && k < KS) {
                    f32x2 wv; wv.x = wt.w[2*k]; wv.y = wt.w[2*k + 1];
                    accm[r] = __builtin_elementwise_fma(wv, mv, accm[r]);
                    accs[r] = __builtin_elementwise_fma(wv, pv, accs[r]);
                }
            }
        }
    }
    #pragma unroll
    for (int r = 0; r < TH; ++r) {
        sm[r][tid + 6] = accm[r];
        sv[r][tid + 6] = accs[r];
    }
    __syncthreads();

    // ---- Phase B: horizontal conv + SSIM map; 1 row x 4 cols per thread.
    //      Two sequential sub-phases (mu then sigma) to cap live registers. ----
    const float C1f = 0.0001f;   // 0.01^2
    const float C2f = 0.0009f;   // 0.03^2
    const int r  = tid >> 7;             // 4 rows x 128 threads (wave-uniform)
    const int c4 = (tid & 127) << 2;     // output col base

    // output col c4+j needs staged idx c4+j+1 .. c4+j+11 -> window elems [j+1..j+11]
    f32x2 cmu[4], csv[4];
    {
        f32x2 xm[16];
        const float4* rpm = (const float4*)&sm[r][c4];   // elem i <-> idx c4+i
        #pragma unroll
        for (int i = 0; i < 8; ++i) {
            const float4 q = rpm[i];
            xm[2*i].x = q.x; xm[2*i].y = q.y; xm[2*i+1].x = q.z; xm[2*i+1].y = q.w;
        }
        #pragma unroll
        for (int j = 0; j < 4; ++j) {
            f32x2 w0; w0.x = wt.w[0]; w0.y = wt.w[1];
            f32x2 m = w0 * xm[j + 1];
            #pragma unroll
            for (int k = 1; k < KS; ++k) {
                f32x2 wv; wv.x = wt.w[2*k]; wv.y = wt.w[2*k + 1];
                m = __builtin_elementwise_fma(wv, xm[j + 1 + k], m);
            }
            cmu[j] = m;
        }
    }
    {
        f32x2 xs[16];
        const float4* rps = (const float4*)&sv[r][c4];
        #pragma unroll
        for (int i = 0; i < 8; ++i) {
            const float4 q = rps[i];
            xs[2*i].x = q.x; xs[2*i].y = q.y; xs[2*i+1].x = q.z; xs[2*i+1].y = q.w;
        }
        #pragma unroll
        for (int j = 0; j < 4; ++j) {
            f32x2 w0; w0.x = wt.w[0]; w0.y = wt.w[1];
            f32x2 m = w0 * xs[j + 1];
            #pragma unroll
            for (int k = 1; k < KS; ++k) {
                f32x2 wv; wv.x = wt.w[2*k]; wv.y = wt.w[2*k + 1];
                m = __builtin_elementwise_fma(wv, xs[j + 1 + k], m);
            }
            csv[j] = m;
        }
    }

    float lsum = 0.f;
    #pragma unroll
    for (int j = 0; j < 4; ++j) {
        const float m1 = cmu[j].x, m2 = cmu[j].y;
        const float mu11 = m1 * m1;
        const float mu22 = m2 * m2;
        const float mu12 = m1 * m2;
        const float t     = mu11 + mu22;
        const float sigpp = csv[j].x - t;            // sigma1_sq + sigma2_sq
        const float sig12 = csv[j].y - mu12;
        const float num = fmaf(2.f, mu12, C1f) * fmaf(2.f, sig12, C2f);
        const float den = (t + C1f) * (sigpp + C2f);
        lsum = fmaf(num, __builtin_amdgcn_rcpf(den), lsum);
    }

    // ---- reduce: wave shuffle, then per-wave partials ----
    #pragma unroll
    for (int off = 32; off > 0; off >>= 1) lsum += __shfl_down(lsum, off);
    if ((tid & 63) == 0) redw[tid >> 6] = lsum;
    __syncthreads();
    if (tid == 0) {
        float t = 0.f;
        #pragma unroll
        for (int w = 0; w < NTHREADS / 64; ++w) t += redw[w];
        const int bid = blockIdx.z * gridDim.y + blockIdx.y;
        bsums[bid] = t;
    }
}

// Final reduce in double (fp32 sequential sum of the 1.26e7-magnitude total
// would exceed the 2.6e-4 threshold).
__global__ __launch_bounds__(256)
void ssim_reduce_kernel(const float4* __restrict__ bsums, int n4,
                        float* __restrict__ out, double inv_count) {
    __shared__ double red[256];
    double acc = 0.0;
    for (int i = threadIdx.x; i < n4; i += 256) {
        const float4 v = bsums[i];
        acc += (double)v.x + (double)v.y + (double)v.z + (double)v.w;
    }
    red[threadIdx.x] = acc;
    __syncthreads();
    #pragma unroll
    for (int off = 128; off > 0; off >>= 1) {
        if (threadIdx.x < off) red[threadIdx.x] += red[threadIdx.x + off];
        __syncthreads();
    }
    if (threadIdx.x == 0) out[0] = (float)(red[0] * inv_count);
}

extern "C" void kernel_launch(void* const* d_in, const int* in_sizes, int n_in,
                              void* d_out, int out_size, void* d_ws, size_t ws_size,
                              hipStream_t stream) {
    const float* img1 = (const float*)d_in[0];
    const float* img2 = (const float*)d_in[1];
    float* out = (float*)d_out;
    float* bsums = (float*)d_ws;

    // Gaussian weights, computed in double like the numpy reference, cast to f32.
    // Duplicated per tap so each tap is a ready-made 64-bit SGPR pair for pk_fma.
    W22 wt;
    {
        double g[KS], sum = 0.0;
        for (int i = 0; i < KS; ++i) {
            const double x = (double)(i - KR);
            g[i] = exp(-(x * x) / (2.0 * 1.5 * 1.5));
            sum += g[i];
        }
        for (int i = 0; i < KS; ++i) {
            wt.w[2*i]     = (float)(g[i] / sum);
            wt.w[2*i + 1] = (float)(g[i] / sum);
        }
    }

    const int NC = 16 * 3;
    const dim3 grid(1, IMG_H / TH, NC);    // 1 x 128 x 48 = 6144 blocks
    const int nblocks = grid.y * grid.z;

    ssim_tile_kernel<<<grid, NTHREADS, 0, stream>>>(img1, img2, bsums, wt);

    const double inv_count = 1.0 / ((double)NC * IMG_H * IMG_W);
    ssim_reduce_kernel<<<1, 256, 0, stream>>>((const float4*)bsums, nblocks / 4,
                                              out, inv_count);
}

// Round 7
// 60.558 us; speedup vs baseline: 1.4400x; 1.3702x over previous
//
#include <hip/hip_runtime.h>
#include <math.h>

#define IMG_H 512
#define IMG_W 512
#define TH 4                 // output rows per block
#define KR 5                 // radius
#define KS 11                // taps
#define NR (TH + 2 * KR)     // 14 input rows per band
#define LW2 524              // f32x2 elems per row: global cols -6..517 at e=col+6
#define NTHREADS 512

typedef float f32x2 __attribute__((ext_vector_type(2)));

struct W22 { float w[2 * KS]; };   // w[2k] == w[2k+1] == gaussian tap k

// 16B-unit XOR swizzle: u = f32x2-pair index within a row (2 f32x2 = 16B unit).
// Spreads the 8 bank-positions so phase-B b128 reads (32B lane stride) are
// conflict-free; phase-A b64 writes stay 2-way (free). XOR of low 3 bits never
// escapes an aligned 8-unit block; the tail block (u>=256) maps to identity.
__device__ __forceinline__ int swz(int u) { return u ^ ((u >> 3) & 7); }

// Fused SSIM band kernel: one 512x4 full-width output band per block.
// LDS: two swizzled f32x2 fields:
//   sm[r][*] = (conv_v(a), conv_v(b))        -> horizontal conv -> (mu1, mu2)
//   sv[r][*] = (conv_v(a^2+b^2), conv_v(ab)) -> (E[a^2+b^2], E[ab])
// Every FMA is a v_pk_fma_f32 (pairs share taps). 33.5 KB LDS -> 4 blocks/CU.
__global__ __launch_bounds__(NTHREADS)
void ssim_tile_kernel(const float* __restrict__ img1, const float* __restrict__ img2,
                      float* __restrict__ bsums, W22 wt) {
    __shared__ __align__(16) f32x2 sm[TH][LW2];   // 16,768 B
    __shared__ __align__(16) f32x2 sv[TH][LW2];   // 16,768 B
    __shared__ float redw[NTHREADS / 64];

    const int row0  = blockIdx.y * TH;
    const int plane = blockIdx.z;
    const float* __restrict__ p1 = img1 + (size_t)plane * (IMG_H * IMG_W);
    const float* __restrict__ p2 = img2 + (size_t)plane * (IMG_H * IMG_W);
    const int tid = threadIdx.x;
    const int r0  = row0 - KR;

    // Zero-fill the 12 alignment-halo cols (e 0..5 = cols -6..-1, 518..523).
    if (tid < 12) {
        const int e = (tid < 6) ? tid : (512 + tid);
        const int slot = swz(e >> 1) * 2 + (e & 1);
        #pragma unroll
        for (int r = 0; r < TH; ++r) {
            sm[r][slot] = (f32x2){0.f, 0.f};
            sv[r][slot] = (f32x2){0.f, 0.f};
        }
    }

    // ---- Phase A: vertical 11-tap conv, one column per thread ----
    // All 28 loads issued up-front at clamped addresses (always in-bounds) so
    // the compiler can batch them; boundary handled by block-uniform selects.
    float av[NR], bv[NR];
    {
        const float* __restrict__ g1 = p1 + tid;
        const float* __restrict__ g2 = p2 + tid;
        #pragma unroll
        for (int j = 0; j < NR; ++j) {
            const int rr  = r0 + j;
            const int rrc = min(max(rr, 0), IMG_H - 1);   // block-uniform scalar
            av[j] = g1[rrc * IMG_W];
            bv[j] = g2[rrc * IMG_W];
        }
    }

    f32x2 accm[TH], accs[TH];
    #pragma unroll
    for (int r = 0; r < TH; ++r) { accm[r] = (f32x2){0.f, 0.f}; accs[r] = (f32x2){0.f, 0.f}; }

    #pragma unroll
    for (int j = 0; j < NR; ++j) {
        const int  rr = r0 + j;
        const bool ok = (rr >= 0) && (rr < IMG_H);        // block-uniform
        const float a = ok ? av[j] : 0.f;
        const float b = ok ? bv[j] : 0.f;
        f32x2 mv; mv.x = a;                mv.y = b;
        f32x2 pv; pv.x = fmaf(a, a, b*b);  pv.y = a * b;
        #pragma unroll
        for (int r = 0; r < TH; ++r) {
            const int k = j - r;                          // compile-time
            if (k >= 0 && k < KS) {
                f32x2 wv; wv.x = wt.w[2*k]; wv.y = wt.w[2*k + 1];
                accm[r] = __builtin_elementwise_fma(wv, mv, accm[r]);
                accs[r] = __builtin_elementwise_fma(wv, pv, accs[r]);
            }
        }
    }
    {
        const int e = tid + 6;
        const int slot = swz(e >> 1) * 2 + (e & 1);
        #pragma unroll
        for (int r = 0; r < TH; ++r) {
            sm[r][slot] = accm[r];
            sv[r][slot] = accs[r];
        }
    }
    __syncthreads();

    // ---- Phase B: horizontal conv + SSIM map; 1 row x 4 cols per thread.
    //      Two sequential sub-phases (mu then sigma) to cap live registers. ----
    const float C1f = 0.0001f;   // 0.01^2
    const float C2f = 0.0009f;   // 0.03^2
    const int r  = tid >> 7;             // 4 rows x 128 threads (wave-uniform)
    const int L  = tid & 127;
    const int u0 = L << 1;               // unit base; elem base c4 = L*4

    // output col c4+j needs staged elems c4+j+1 .. c4+j+11 -> window [j+1..j+11]
    f32x2 cmu[4], csv[4];
    {
        f32x2 xm[16];
        const float4* rpm = (const float4*)&sm[r][0];
        #pragma unroll
        for (int i = 0; i < 8; ++i) {
            const float4 q = rpm[swz(u0 + i)];            // elems 2(u0+i), +1
            xm[2*i]   = (f32x2){q.x, q.y};
            xm[2*i+1] = (f32x2){q.z, q.w};
        }
        #pragma unroll
        for (int j = 0; j < 4; ++j) {
            f32x2 w0; w0.x = wt.w[0]; w0.y = wt.w[1];
            f32x2 m = w0 * xm[j + 1];
            #pragma unroll
            for (int k = 1; k < KS; ++k) {
                f32x2 wv; wv.x = wt.w[2*k]; wv.y = wt.w[2*k + 1];
                m = __builtin_elementwise_fma(wv, xm[j + 1 + k], m);
            }
            cmu[j] = m;
        }
    }
    {
        f32x2 xs[16];
        const float4* rps = (const float4*)&sv[r][0];
        #pragma unroll
        for (int i = 0; i < 8; ++i) {
            const float4 q = rps[swz(u0 + i)];
            xs[2*i]   = (f32x2){q.x, q.y};
            xs[2*i+1] = (f32x2){q.z, q.w};
        }
        #pragma unroll
        for (int j = 0; j < 4; ++j) {
            f32x2 w0; w0.x = wt.w[0]; w0.y = wt.w[1];
            f32x2 m = w0 * xs[j + 1];
            #pragma unroll
            for (int k = 1; k < KS; ++k) {
                f32x2 wv; wv.x = wt.w[2*k]; wv.y = wt.w[2*k + 1];
                m = __builtin_elementwise_fma(wv, xs[j + 1 + k], m);
            }
            csv[j] = m;
        }
    }

    float lsum = 0.f;
    #pragma unroll
    for (int j = 0; j < 4; ++j) {
        const float m1 = cmu[j].x, m2 = cmu[j].y;
        const float mu11 = m1 * m1;
        const float mu22 = m2 * m2;
        const float mu12 = m1 * m2;
        const float t     = mu11 + mu22;
        const float sigpp = csv[j].x - t;            // sigma1_sq + sigma2_sq
        const float sig12 = csv[j].y - mu12;
        const float num = fmaf(2.f, mu12, C1f) * fmaf(2.f, sig12, C2f);
        const float den = (t + C1f) * (sigpp + C2f);
        lsum = fmaf(num, __builtin_amdgcn_rcpf(den), lsum);
    }

    // ---- reduce: wave shuffle, then per-wave partials ----
    #pragma unroll
    for (int off = 32; off > 0; off >>= 1) lsum += __shfl_down(lsum, off);
    if ((tid & 63) == 0) redw[tid >> 6] = lsum;
    __syncthreads();
    if (tid == 0) {
        float t = 0.f;
        #pragma unroll
        for (int w = 0; w < NTHREADS / 64; ++w) t += redw[w];
        const int bid = blockIdx.z * gridDim.y + blockIdx.y;
        bsums[bid] = t;
    }
}

// Final reduce in double (fp32 sequential sum of the 1.26e7-magnitude total
// would exceed the 2.6e-4 threshold).
__global__ __launch_bounds__(256)
void ssim_reduce_kernel(const float4* __restrict__ bsums, int n4,
                        float* __restrict__ out, double inv_count) {
    __shared__ double red[256];
    double acc = 0.0;
    for (int i = threadIdx.x; i < n4; i += 256) {
        const float4 v = bsums[i];
        acc += (double)v.x + (double)v.y + (double)v.z + (double)v.w;
    }
    red[threadIdx.x] = acc;
    __syncthreads();
    #pragma unroll
    for (int off = 128; off > 0; off >>= 1) {
        if (threadIdx.x < off) red[threadIdx.x] += red[threadIdx.x + off];
        __syncthreads();
    }
    if (threadIdx.x == 0) out[0] = (float)(red[0] * inv_count);
}

extern "C" void kernel_launch(void* const* d_in, const int* in_sizes, int n_in,
                              void* d_out, int out_size, void* d_ws, size_t ws_size,
                              hipStream_t stream) {
    const float* img1 = (const float*)d_in[0];
    const float* img2 = (const float*)d_in[1];
    float* out = (float*)d_out;
    float* bsums = (float*)d_ws;

    // Gaussian weights, computed in double like the numpy reference, cast to f32.
    // Duplicated per tap so each tap is a ready-made 64-bit SGPR pair for pk_fma.
    W22 wt;
    {
        double g[KS], sum = 0.0;
        for (int i = 0; i < KS; ++i) {
            const double x = (double)(i - KR);
            g[i] = exp(-(x * x) / (2.0 * 1.5 * 1.5));
            sum += g[i];
        }
        for (int i = 0; i < KS; ++i) {
            wt.w[2*i]     = (float)(g[i] / sum);
            wt.w[2*i + 1] = (float)(g[i] / sum);
        }
    }

    const int NC = 16 * 3;
    const dim3 grid(1, IMG_H / TH, NC);    // 1 x 128 x 48 = 6144 blocks
    const int nblocks = grid.y * grid.z;

    ssim_tile_kernel<<<grid, NTHREADS, 0, stream>>>(img1, img2, bsums, wt);

    const double inv_count = 1.0 / ((double)NC * IMG_H * IMG_W);
    ssim_reduce_kernel<<<1, 256, 0, stream>>>((const float4*)bsums, nblocks / 4,
                                              out, inv_count);
}

// Round 8
// 44.079 us; speedup vs baseline: 1.9783x; 1.3738x over previous
//
#include <hip/hip_runtime.h>
#include <math.h>

#define IMG_H 512
#define IMG_W 512
#define TH 4                 // output rows per block
#define KR 5                 // radius
#define KS 11                // taps
#define NR (TH + 2 * KR)     // 14 input rows per band
#define LW2 524              // f32x2 elems per row: global cols -6..517 at e=col+6
#define NTHREADS 512
#define NBANDS (IMG_H / TH)  // 128
#define NPLANES 48
#define NBLK (NBANDS * NPLANES)   // 6144, divisible by 8

typedef float f32x2 __attribute__((ext_vector_type(2)));

struct W22 { float w[2 * KS]; };   // w[2k] == w[2k+1] == gaussian tap k

// 16B-unit XOR swizzle: u = f32x2-pair index within a row (2 f32x2 = 16B unit).
// Spreads bank positions so phase-B b128 reads (32B lane stride) are
// conflict-free; phase-A b64 writes stay ~free.
__device__ __forceinline__ int swz(int u) { return u ^ ((u >> 3) & 7); }

// Fused SSIM band kernel: one 512x4 full-width output band per block.
// LDS: two swizzled f32x2 fields:
//   sm[r][*] = (conv_v(a), conv_v(b))        -> horizontal conv -> (mu1, mu2)
//   sv[r][*] = (conv_v(a^2+b^2), conv_v(ab)) -> (E[a^2+b^2], E[ab])
// Every FMA is a v_pk_fma_f32 (pairs share taps). 33.5 KB LDS -> 4 blocks/CU.
// Flat grid + XCD-aware swizzle: each XCD processes whole planes with y-bands
// in ascending order so band halos hit that XCD's own L2.
__global__ __launch_bounds__(NTHREADS)
void ssim_tile_kernel(const float* __restrict__ img1, const float* __restrict__ img2,
                      float* __restrict__ bsums, W22 wt) {
    __shared__ __align__(16) f32x2 sm[TH][LW2];   // 16,768 B
    __shared__ __align__(16) f32x2 sv[TH][LW2];   // 16,768 B
    __shared__ float redw[NTHREADS / 64];

    // XCD-aware bijective remap (NBLK % 8 == 0): XCD (bid&7) sweeps contiguous
    // sbid range => adjacent y-bands co-resident in one XCD's L2.
    const int bid   = blockIdx.x;
    const int sbid  = (bid & 7) * (NBLK / 8) + (bid >> 3);
    const int plane = sbid >> 7;          // sbid / NBANDS
    const int band  = sbid & (NBANDS - 1);

    const int row0 = band * TH;
    const float* __restrict__ p1 = img1 + (size_t)plane * (IMG_H * IMG_W);
    const float* __restrict__ p2 = img2 + (size_t)plane * (IMG_H * IMG_W);
    const int tid = threadIdx.x;
    const int r0  = row0 - KR;

    // Zero-fill the 12 alignment-halo cols (e 0..5 = cols -6..-1, 518..523).
    if (tid < 12) {
        const int e = (tid < 6) ? tid : (512 + tid);
        const int slot = swz(e >> 1) * 2 + (e & 1);
        #pragma unroll
        for (int r = 0; r < TH; ++r) {
            sm[r][slot] = (f32x2){0.f, 0.f};
            sv[r][slot] = (f32x2){0.f, 0.f};
        }
    }

    // ---- Phase A: vertical 11-tap conv, one column per thread ----
    // Interior bands (124/128): unconditional batched loads, no clamps/selects.
    float av[NR], bv[NR];
    {
        const float* __restrict__ g1 = p1 + tid;
        const float* __restrict__ g2 = p2 + tid;
        if (r0 >= 0 && r0 + NR <= IMG_H) {
            #pragma unroll
            for (int j = 0; j < NR; ++j) {
                av[j] = g1[(r0 + j) * IMG_W];
                bv[j] = g2[(r0 + j) * IMG_W];
            }
        } else {
            #pragma unroll
            for (int j = 0; j < NR; ++j) {
                const int  rr  = r0 + j;
                const bool ok  = (rr >= 0) && (rr < IMG_H);   // block-uniform
                const int  rrc = min(max(rr, 0), IMG_H - 1);
                const float a = g1[rrc * IMG_W];
                const float b = g2[rrc * IMG_W];
                av[j] = ok ? a : 0.f;
                bv[j] = ok ? b : 0.f;
            }
        }
    }

    f32x2 accm[TH], accs[TH];
    #pragma unroll
    for (int r = 0; r < TH; ++r) { accm[r] = (f32x2){0.f, 0.f}; accs[r] = (f32x2){0.f, 0.f}; }

    #pragma unroll
    for (int j = 0; j < NR; ++j) {
        const float a = av[j], b = bv[j];
        f32x2 mv; mv.x = a;                mv.y = b;
        f32x2 pv; pv.x = fmaf(a, a, b*b);  pv.y = a * b;
        #pragma unroll
        for (int r = 0; r < TH; ++r) {
            const int k = j - r;                          // compile-time
            if (k >= 0 && k < KS) {
                f32x2 wv; wv.x = wt.w[2*k]; wv.y = wt.w[2*k + 1];
                accm[r] = __builtin_elementwise_fma(wv, mv, accm[r]);
                accs[r] = __builtin_elementwise_fma(wv, pv, accs[r]);
            }
        }
    }
    {
        const int e = tid + 6;
        const int slot = swz(e >> 1) * 2 + (e & 1);
        #pragma unroll
        for (int r = 0; r < TH; ++r) {
            sm[r][slot] = accm[r];
            sv[r][slot] = accs[r];
        }
    }
    __syncthreads();

    // ---- Phase B: horizontal conv + SSIM map; 1 row x 4 cols per thread.
    //      Two sequential sub-phases (mu then sigma) to cap live registers. ----
    const float C1f = 0.0001f;   // 0.01^2
    const float C2f = 0.0009f;   // 0.03^2
    const int r  = tid >> 7;             // 4 rows x 128 threads (wave-uniform)
    const int L  = tid & 127;
    const int u0 = L << 1;               // unit base; elem base c4 = L*4

    // Hoist the 8 swizzled unit indices (shared by both sub-phases).
    int su[8];
    #pragma unroll
    for (int i = 0; i < 8; ++i) su[i] = swz(u0 + i);

    // output col c4+j needs staged elems c4+j+1 .. c4+j+11 -> window [j+1..j+11]
    f32x2 cmu[4], csv[4];
    {
        f32x2 xm[16];
        const float4* rpm = (const float4*)&sm[r][0];
        #pragma unroll
        for (int i = 0; i < 8; ++i) {
            const float4 q = rpm[su[i]];                  // elems 2(u0+i), +1
            xm[2*i]   = (f32x2){q.x, q.y};
            xm[2*i+1] = (f32x2){q.z, q.w};
        }
        #pragma unroll
        for (int j = 0; j < 4; ++j) {
            f32x2 w0; w0.x = wt.w[0]; w0.y = wt.w[1];
            f32x2 m = w0 * xm[j + 1];
            #pragma unroll
            for (int k = 1; k < KS; ++k) {
                f32x2 wv; wv.x = wt.w[2*k]; wv.y = wt.w[2*k + 1];
                m = __builtin_elementwise_fma(wv, xm[j + 1 + k], m);
            }
            cmu[j] = m;
        }
    }
    {
        f32x2 xs[16];
        const float4* rps = (const float4*)&sv[r][0];
        #pragma unroll
        for (int i = 0; i < 8; ++i) {
            const float4 q = rps[su[i]];
            xs[2*i]   = (f32x2){q.x, q.y};
            xs[2*i+1] = (f32x2){q.z, q.w};
        }
        #pragma unroll
        for (int j = 0; j < 4; ++j) {
            f32x2 w0; w0.x = wt.w[0]; w0.y = wt.w[1];
            f32x2 m = w0 * xs[j + 1];
            #pragma unroll
            for (int k = 1; k < KS; ++k) {
                f32x2 wv; wv.x = wt.w[2*k]; wv.y = wt.w[2*k + 1];
                m = __builtin_elementwise_fma(wv, xs[j + 1 + k], m);
            }
            csv[j] = m;
        }
    }

    float lsum = 0.f;
    #pragma unroll
    for (int j = 0; j < 4; ++j) {
        const float m1 = cmu[j].x, m2 = cmu[j].y;
        const float mu11 = m1 * m1;
        const float mu22 = m2 * m2;
        const float mu12 = m1 * m2;
        const float t     = mu11 + mu22;
        const float sigpp = csv[j].x - t;            // sigma1_sq + sigma2_sq
        const float sig12 = csv[j].y - mu12;
        const float num = fmaf(2.f, mu12, C1f) * fmaf(2.f, sig12, C2f);
        const float den = (t + C1f) * (sigpp + C2f);
        lsum = fmaf(num, __builtin_amdgcn_rcpf(den), lsum);
    }

    // ---- reduce: wave shuffle, then per-wave partials ----
    #pragma unroll
    for (int off = 32; off > 0; off >>= 1) lsum += __shfl_down(lsum, off);
    if ((tid & 63) == 0) redw[tid >> 6] = lsum;
    __syncthreads();
    if (tid == 0) {
        float t = 0.f;
        #pragma unroll
        for (int w = 0; w < NTHREADS / 64; ++w) t += redw[w];
        bsums[sbid] = t;
    }
}

// Final reduce in double (fp32 sequential sum of the 1.26e7-magnitude total
// would exceed the 2.6e-4 threshold).
__global__ __launch_bounds__(256)
void ssim_reduce_kernel(const float4* __restrict__ bsums, int n4,
                        float* __restrict__ out, double inv_count) {
    __shared__ double red[256];
    double acc = 0.0;
    for (int i = threadIdx.x; i < n4; i += 256) {
        const float4 v = bsums[i];
        acc += (double)v.x + (double)v.y + (double)v.z + (double)v.w;
    }
    red[threadIdx.x] = acc;
    __syncthreads();
    #pragma unroll
    for (int off = 128; off > 0; off >>= 1) {
        if (threadIdx.x < off) red[threadIdx.x] += red[threadIdx.x + off];
        __syncthreads();
    }
    if (threadIdx.x == 0) out[0] = (float)(red[0] * inv_count);
}

extern "C" void kernel_launch(void* const* d_in, const int* in_sizes, int n_in,
                              void* d_out, int out_size, void* d_ws, size_t ws_size,
                              hipStream_t stream) {
    const float* img1 = (const float*)d_in[0];
    const float* img2 = (const float*)d_in[1];
    float* out = (float*)d_out;
    float* bsums = (float*)d_ws;

    // Gaussian weights, computed in double like the numpy reference, cast to f32.
    // Duplicated per tap so each tap is a ready-made 64-bit SGPR pair for pk_fma.
    W22 wt;
    {
        double g[KS], sum = 0.0;
        for (int i = 0; i < KS; ++i) {
            const double x = (double)(i - KR);
            g[i] = exp(-(x * x) / (2.0 * 1.5 * 1.5));
            sum += g[i];
        }
        for (int i = 0; i < KS; ++i) {
            wt.w[2*i]     = (float)(g[i] / sum);
            wt.w[2*i + 1] = (float)(g[i] / sum);
        }
    }

    ssim_tile_kernel<<<dim3(NBLK), NTHREADS, 0, stream>>>(img1, img2, bsums, wt);

    const double inv_count = 1.0 / ((double)NPLANES * IMG_H * IMG_W);
    ssim_reduce_kernel<<<1, 256, 0, stream>>>((const float4*)bsums, NBLK / 4,
                                              out, inv_count);
}

// Round 10
// 43.802 us; speedup vs baseline: 1.9908x; 1.0063x over previous
//
#include <hip/hip_runtime.h>
#include <math.h>

#define IMG_H 512
#define IMG_W 512
#define TH 4                 // output rows per block
#define KR 5                 // radius
#define KS 11                // taps
#define NR (TH + 2 * KR)     // 14 input rows per band
#define LW2 524              // f32x2 elems per row: global cols -6..517 at e=col+6
#define NTHREADS 512
#define NBANDS (IMG_H / TH)  // 128
#define NPLANES 48
#define NBLK (NBANDS * NPLANES)   // 6144, divisible by 8

typedef float f32x2 __attribute__((ext_vector_type(2)));

struct W22 { float w[2 * KS]; };   // w[2k] == w[2k+1] == gaussian tap k

// Keep a value live/materialized here: forces the compiler to issue the
// producing load before this point instead of sinking it into the consumer
// loop (which would serialize load->use latency per iteration).
#define PIN(x) asm volatile("" :: "v"(x))

// 16B-unit XOR swizzle: u = f32x2-pair index within a row (2 f32x2 = 16B unit).
__device__ __forceinline__ int swz(int u) { return u ^ ((u >> 3) & 7); }

// Fused SSIM band kernel: one 512x4 full-width output band per block.
// LDS: two swizzled f32x2 fields:
//   sm[r][*] = (conv_v(a), conv_v(b))        -> horizontal conv -> (mu1, mu2)
//   sv[r][*] = (conv_v(a^2+b^2), conv_v(ab)) -> (E[a^2+b^2], E[ab])
// Every FMA is a v_pk_fma_f32. 33.5 KB LDS + VGPR<=64 -> 4 blocks/CU.
__global__ __launch_bounds__(NTHREADS, 8)
void ssim_tile_kernel(const float* __restrict__ img1, const float* __restrict__ img2,
                      float* __restrict__ bsums, W22 wt) {
    __shared__ __align__(16) f32x2 sm[TH][LW2];   // 16,768 B
    __shared__ __align__(16) f32x2 sv[TH][LW2];   // 16,768 B
    __shared__ float redw[NTHREADS / 64];

    // XCD-aware bijective remap (NBLK % 8 == 0): XCD (bid&7) sweeps contiguous
    // sbid range => adjacent y-bands co-resident in one XCD's L2.
    const int bid   = blockIdx.x;
    const int sbid  = (bid & 7) * (NBLK / 8) + (bid >> 3);
    const int plane = sbid >> 7;          // sbid / NBANDS
    const int band  = sbid & (NBANDS - 1);

    const int row0 = band * TH;
    const float* __restrict__ p1 = img1 + (size_t)plane * (IMG_H * IMG_W);
    const float* __restrict__ p2 = img2 + (size_t)plane * (IMG_H * IMG_W);
    const int tid = threadIdx.x;
    const int r0  = row0 - KR;

    // Zero-fill the 12 alignment-halo cols (e 0..5 = cols -6..-1, 518..523).
    if (tid < 12) {
        const int e = (tid < 6) ? tid : (512 + tid);
        const int slot = swz(e >> 1) * 2 + (e & 1);
        #pragma unroll
        for (int r = 0; r < TH; ++r) {
            sm[r][slot] = (f32x2){0.f, 0.f};
            sv[r][slot] = (f32x2){0.f, 0.f};
        }
    }

    // ---- Phase A: vertical 11-tap conv, one column per thread ----
    // All 28 loads issued up-front, pinned so they stay batched (one wait
    // point) instead of being re-rolled into the FMA loop.
    float av[NR], bv[NR];
    {
        const float* __restrict__ g1 = p1 + tid;
        const float* __restrict__ g2 = p2 + tid;
        if (r0 >= 0 && r0 + NR <= IMG_H) {
            #pragma unroll
            for (int j = 0; j < NR; ++j) {
                av[j] = g1[(r0 + j) * IMG_W];
                bv[j] = g2[(r0 + j) * IMG_W];
            }
        } else {
            #pragma unroll
            for (int j = 0; j < NR; ++j) {
                const int  rr  = r0 + j;
                const bool ok  = (rr >= 0) && (rr < IMG_H);   // block-uniform
                const int  rrc = min(max(rr, 0), IMG_H - 1);
                const float a = g1[rrc * IMG_W];
                const float b = g2[rrc * IMG_W];
                av[j] = ok ? a : 0.f;
                bv[j] = ok ? b : 0.f;
            }
        }
        #pragma unroll
        for (int j = 0; j < NR; ++j) { PIN(av[j]); PIN(bv[j]); }
    }

    f32x2 accm[TH], accs[TH];
    #pragma unroll
    for (int r = 0; r < TH; ++r) { accm[r] = (f32x2){0.f, 0.f}; accs[r] = (f32x2){0.f, 0.f}; }

    #pragma unroll
    for (int j = 0; j < NR; ++j) {
        const float a = av[j], b = bv[j];
        f32x2 mv; mv.x = a;                mv.y = b;
        f32x2 pv; pv.x = fmaf(a, a, b*b);  pv.y = a * b;
        #pragma unroll
        for (int r = 0; r < TH; ++r) {
            const int k = j - r;                          // compile-time
            if (k >= 0 && k < KS) {
                f32x2 wv; wv.x = wt.w[2*k]; wv.y = wt.w[2*k + 1];
                accm[r] = __builtin_elementwise_fma(wv, mv, accm[r]);
                accs[r] = __builtin_elementwise_fma(wv, pv, accs[r]);
            }
        }
    }
    {
        const int e = tid + 6;
        const int slot = swz(e >> 1) * 2 + (e & 1);
        #pragma unroll
        for (int r = 0; r < TH; ++r) {
            sm[r][slot] = accm[r];
            sv[r][slot] = accs[r];
        }
    }
    __syncthreads();

    // ---- Phase B: horizontal conv + SSIM map; 1 row x 4 cols per thread ----
    const float C1f = 0.0001f;   // 0.01^2
    const float C2f = 0.0009f;   // 0.03^2
    const int r  = tid >> 7;             // 4 rows x 128 threads (wave-uniform)
    const int L  = tid & 127;
    const int u0 = L << 1;               // unit base; elem base c4 = L*4

    // Hoist the 8 swizzled unit indices (shared by both sub-phases).
    int su[8];
    #pragma unroll
    for (int i = 0; i < 8; ++i) su[i] = swz(u0 + i);

    // output col c4+j needs staged elems c4+j+1 .. c4+j+11 -> window [j+1..j+11]
    f32x2 cmu[4], csv[4];
    {
        f32x2 xm[16];
        const float4* rpm = (const float4*)&sm[r][0];
        #pragma unroll
        for (int i = 0; i < 8; ++i) {
            const float4 q = rpm[su[i]];                  // elems 2(u0+i), +1
            xm[2*i]   = (f32x2){q.x, q.y};
            xm[2*i+1] = (f32x2){q.z, q.w};
        }
        #pragma unroll
        for (int i = 0; i < 16; ++i) { PIN(xm[i].x); PIN(xm[i].y); }
        #pragma unroll
        for (int j = 0; j < 4; ++j) {
            f32x2 w0; w0.x = wt.w[0]; w0.y = wt.w[1];
            f32x2 m = w0 * xm[j + 1];
            #pragma unroll
            for (int k = 1; k < KS; ++k) {
                f32x2 wv; wv.x = wt.w[2*k]; wv.y = wt.w[2*k + 1];
                m = __builtin_elementwise_fma(wv, xm[j + 1 + k], m);
            }
            cmu[j] = m;
        }
    }
    {
        f32x2 xs[16];
        const float4* rps = (const float4*)&sv[r][0];
        #pragma unroll
        for (int i = 0; i < 8; ++i) {
            const float4 q = rps[su[i]];
            xs[2*i]   = (f32x2){q.x, q.y};
            xs[2*i+1] = (f32x2){q.z, q.w};
        }
        #pragma unroll
        for (int i = 0; i < 16; ++i) { PIN(xs[i].x); PIN(xs[i].y); }
        #pragma unroll
        for (int j = 0; j < 4; ++j) {
            f32x2 w0; w0.x = wt.w[0]; w0.y = wt.w[1];
            f32x2 m = w0 * xs[j + 1];
            #pragma unroll
            for (int k = 1; k < KS; ++k) {
                f32x2 wv; wv.x = wt.w[2*k]; wv.y = wt.w[2*k + 1];
                m = __builtin_elementwise_fma(wv, xs[j + 1 + k], m);
            }
            csv[j] = m;
        }
    }

    float lsum = 0.f;
    #pragma unroll
    for (int j = 0; j < 4; ++j) {
        const float m1 = cmu[j].x, m2 = cmu[j].y;
        const float mu11 = m1 * m1;
        const float mu22 = m2 * m2;
        const float mu12 = m1 * m2;
        const float t     = mu11 + mu22;
        const float sigpp = csv[j].x - t;            // sigma1_sq + sigma2_sq
        const float sig12 = csv[j].y - mu12;
        const float num = fmaf(2.f, mu12, C1f) * fmaf(2.f, sig12, C2f);
        const float den = (t + C1f) * (sigpp + C2f);
        lsum = fmaf(num, __builtin_amdgcn_rcpf(den), lsum);
    }

    // ---- reduce: wave shuffle, then per-wave partials ----
    #pragma unroll
    for (int off = 32; off > 0; off >>= 1) lsum += __shfl_down(lsum, off);
    if ((tid & 63) == 0) redw[tid >> 6] = lsum;
    __syncthreads();
    if (tid == 0) {
        float t = 0.f;
        #pragma unroll
        for (int w = 0; w < NTHREADS / 64; ++w) t += redw[w];
        bsums[sbid] = t;
    }
}

// Final reduce in double (fp32 sequential sum of the 1.26e7-magnitude total
// would exceed the 2.6e-4 threshold).
__global__ __launch_bounds__(256)
void ssim_reduce_kernel(const float4* __restrict__ bsums, int n4,
                        float* __restrict__ out, double inv_count) {
    __shared__ double red[256];
    double acc = 0.0;
    for (int i = threadIdx.x; i < n4; i += 256) {
        const float4 v = bsums[i];
        acc += (double)v.x + (double)v.y + (double)v.z + (double)v.w;
    }
    red[threadIdx.x] = acc;
    __syncthreads();
    #pragma unroll
    for (int off = 128; off > 0; off >>= 1) {
        if (threadIdx.x < off) red[threadIdx.x] += red[threadIdx.x + off];
        __syncthreads();
    }
    if (threadIdx.x == 0) out[0] = (float)(red[0] * inv_count);
}

extern "C" void kernel_launch(void* const* d_in, const int* in_sizes, int n_in,
                              void* d_out, int out_size, void* d_ws, size_t ws_size,
                              hipStream_t stream) {
    const float* img1 = (const float*)d_in[0];
    const float* img2 = (const float*)d_in[1];
    float* out = (float*)d_out;
    float* bsums = (float*)d_ws;

    // Gaussian weights, computed in double like the numpy reference, cast to f32.
    // Duplicated per tap so each tap is a ready-made 64-bit SGPR pair for pk_fma.
    W22 wt;
    {
        double g[KS], sum = 0.0;
        for (int i = 0; i < KS; ++i) {
            const double x = (double)(i - KR);
            g[i] = exp(-(x * x) / (2.0 * 1.5 * 1.5));
            sum += g[i];
        }
        for (int i = 0; i < KS; ++i) {
            wt.w[2*i]     = (float)(g[i] / sum);
            wt.w[2*i + 1] = (float)(g[i] / sum);
        }
    }

    ssim_tile_kernel<<<dim3(NBLK), NTHREADS, 0, stream>>>(img1, img2, bsums, wt);

    const double inv_count = 1.0 / ((double)NPLANES * IMG_H * IMG_W);
    ssim_reduce_kernel<<<1, 256, 0, stream>>>((const float4*)bsums, NBLK / 4,
                                              out, inv_count);
}